// Round 1
// baseline (94.846 us; speedup 1.0000x reference)
//
#include <hip/hip_runtime.h>

// NeuralCA: out = clip(x + sum_k sigmoid(10*(conv3x3_k(x) - r_k)) * (p_k - x), 0, 1)
// B=16, H=W=512, NK=16, fp32.
//
// R5 theory: metric 91.3us = ~43us harness ws-fill (256MiB poison, visible as the
// fillBufferAligned top-5) + ~2.7us out poison + nca_kernel ~40us. Kernel issue
// floor is ~11us => ~75% stall. Causes: (a) VGPR alloc in the 65..128 band ->
// only 4 waves/SIMD resident (occupancy halves at 64/128/256); (b) every uniform
// constant was broadcast into a VGPR pair for v_pk_* (2 v_movs x 11 consts x 16k
// = ~350 movs/thread) and held 22 VGPRs live.
// Fix: prep kernel duplicates constants into ws as float2 {v,v} with -G2 folded
// into weights and +G2*r as bias -> main kernel s_loads them into SGPR PAIRS that
// feed v_pk_fma_f32 directly (0 VGPRs, 0 movs, z = n + c2 is one pk add).
// Tile shrinks to 2x2 so persistent state (sl[4][3]=24 + acc 8 + misc) fits
// comfortably under 64 VGPRs -> __launch_bounds__(256,8) = 8 waves/SIMD.

#define NK 16
#define BATCH 16
#define H 512
#define W 512
#define G2 14.4269504088896340f   // GAIN(=10) * log2(e)

typedef float f2 __attribute__((ext_vector_type(2)));

#if __has_builtin(__builtin_amdgcn_exp2f)
#define EXP2F(x) __builtin_amdgcn_exp2f(x)
#else
#define EXP2F(x) exp2f(x)
#endif

#if __has_builtin(__builtin_elementwise_fma)
#define FMA2(a, b, c) __builtin_elementwise_fma((a), (b), (c))
#else
#define FMA2(a, b, c) ((a) * (b) + (c))   // fp-contract=fast folds to fma.v2f32
#endif

static __device__ __forceinline__ f2 bc2(float s) { f2 r; r.x = s; r.y = s; return r; }

// Constant address space -> guaranteed s_load (SGPR-pair broadcast for float2)
typedef const __attribute__((address_space(4))) f2 cf2;

// ---------------------------------------------------------------------------
// Prep: pack duplicated constants into ws.
// Layout per k (11 x float2): [0..8] = {-G2*w, -G2*w}, [9] = {G2*r, G2*r},
//                             [10] = {p, p}.
// z = sum_taps (-G2*w)*x + G2*r  ==  -G2*(N - r);  sigmoid = 1/(1 + 2^z).
// ---------------------------------------------------------------------------
__global__ void nca_prep(const float* __restrict__ kernels,
                         const float* __restrict__ reactants,
                         const float* __restrict__ products,
                         float2* __restrict__ cw)
{
    const int t = threadIdx.x;
    if (t < NK * 11) {
        const int k = t / 11;
        const int j = t % 11;
        float v;
        if (j < 9)        v = -G2 * kernels[k * 9 + j];
        else if (j == 9)  v =  G2 * reactants[k];
        else              v =  products[k];
        cw[t] = make_float2(v, v);
    }
}

// ---------------------------------------------------------------------------
// Main: one thread per 2x2 pixel tile. 16 * 256 * 256 = 2^20 threads.
// ---------------------------------------------------------------------------
__global__ __launch_bounds__(256, 8) void nca_kernel(
    const float* __restrict__ x,
    const float2* __restrict__ cw_,
    float* __restrict__ out)
{
    const int idx = blockIdx.x * blockDim.x + threadIdx.x;
    const int w2 = (idx & 255) << 1;         // tile start col (256 tiles/row)
    const int h0 = ((idx >> 8) & 255) << 1;  // tile start row
    const int b  = idx >> 16;

    const float* xb = x + (size_t)b * (H * W);

    // 4x4 register window (rows h0-1..h0+2, cols w2-1..w2+2) held directly as
    // shifted pairs: sl[r][c] = {v[r][c], v[r][c+1]}, c = 0..2.
    // Output pair (local cols 1,2): tap c of row r uses sl[r][c]; center x pair
    // for output row py is sl[py+1][1].
    f2 sl[4][3];
#pragma unroll
    for (int r = 0; r < 4; ++r) {
        const int row = h0 + r - 1;
        if (row >= 0 && row < H) {
            const float* xr = xb + row * W;
            const float2 c = *(const float2*)(xr + w2);       // 8B aligned
            const float lft = (w2 > 0)     ? xr[w2 - 1] : 0.0f;  // zero pad left
            const float rgt = (w2 + 2 < W) ? xr[w2 + 2] : 0.0f;  // zero pad right
            sl[r][0].x = lft; sl[r][0].y = c.x;
            sl[r][1].x = c.x; sl[r][1].y = c.y;
            sl[r][2].x = c.y; sl[r][2].y = rgt;
        } else {
#pragma unroll
            for (int c = 0; c < 3; ++c) sl[r][c] = bc2(0.0f);  // zero pad top/bot
        }
    }

    cf2* cw = (cf2*)cw_;

    // delta = (sum_k sig_k*p_k) - x*(sum_k sig_k)
    f2 s0[2], s1[2];
    s0[0] = bc2(0.0f); s0[1] = bc2(0.0f);
    s1[0] = bc2(0.0f); s1[1] = bc2(0.0f);

    const f2 one = bc2(1.0f);

#pragma unroll
    for (int k = 0; k < NK; ++k) {
        // All uniform: s_load_dwordx2 -> SGPR pairs, consumed directly by VOP3P.
        f2 wk[9];
#pragma unroll
        for (int i = 0; i < 9; ++i) wk[i] = cw[k * 11 + i];
        const f2 c2 = cw[k * 11 + 9];
        const f2 pk = cw[k * 11 + 10];

#pragma unroll
        for (int py = 0; py < 2; ++py) {
            f2 n = bc2(0.0f);
#pragma unroll
            for (int r = 0; r < 3; ++r)
#pragma unroll
                for (int c = 0; c < 3; ++c)
                    n = FMA2(sl[py + r][c], wk[r * 3 + c], n);  // 9 pk fma
            const f2 z = n + c2;                     // pk add (sgpr-pair src)
            f2 e;
            e.x = EXP2F(z.x);                        // v_exp_f32 x2
            e.y = EXP2F(z.y);
            const f2 d = e + one;                    // pk add
            f2 sig;
            sig.x = __builtin_amdgcn_rcpf(d.x);      // v_rcp_f32 x2
            sig.y = __builtin_amdgcn_rcpf(d.y);
            s0[py] = s0[py] + sig;                   // pk add
            s1[py] = FMA2(sig, pk, s1[py]);          // pk fma (sgpr-pair src)
        }
    }

#pragma unroll
    for (int py = 0; py < 2; ++py) {
        const f2 xv = sl[py + 1][1];                 // center pixels of pair
        f2 res = FMA2(-xv, s0[py], xv + s1[py]);
        res.x = fminf(fmaxf(res.x, 0.0f), 1.0f);
        res.y = fminf(fmaxf(res.y, 0.0f), 1.0f);
        *(float2*)(out + ((size_t)(b * H + h0 + py) * W + w2)) =
            make_float2(res.x, res.y);
    }
}

extern "C" void kernel_launch(void* const* d_in, const int* in_sizes, int n_in,
                              void* d_out, int out_size, void* d_ws, size_t ws_size,
                              hipStream_t stream) {
    const float* x         = (const float*)d_in[0];
    const float* kernels   = (const float*)d_in[1];
    const float* reactants = (const float*)d_in[2];
    const float* products  = (const float*)d_in[3];
    float* out = (float*)d_out;
    float2* cw = (float2*)d_ws;   // 176 * 8B = 1408 B of workspace

    nca_prep<<<1, 192, 0, stream>>>(kernels, reactants, products, cw);

    const int total_tiles = BATCH * (H / 2) * (W / 2);  // 2^20
    nca_kernel<<<total_tiles / 256, 256, 0, stream>>>(x, cw, out);
}